// Round 1
// baseline (90.927 us; speedup 1.0000x reference)
//
#include <hip/hip_runtime.h>
#include <math.h>

// Problem constants
#define BB 2
#define LL 1024
#define SS 1024
#define HH 8
#define DD 64
#define PP 4

// Tiling for attn kernel
#define TL 32        // l-rows per block
#define TS 128       // s per tile
#define NT (SS/TS)   // 8 tiles

// cos(2*pi*x) via hardware v_cos (input in revolutions)
#if __has_builtin(__builtin_amdgcn_cosf)
#define COS2PI(x) __builtin_amdgcn_cosf(x)
#else
#define COS2PI(x) __cosf((x) * 6.283185307179586f)
#endif
#if __has_builtin(__builtin_amdgcn_exp2f)
#define EXP2F(x) __builtin_amdgcn_exp2f(x)
#else
#define EXP2F(x) exp2f(x)
#endif

// params are pre-scaled by 1/(4*pi): q' = tanh(...)/4, so
// cos(2*pi*(q'-k')) = cos(0.5*(q_param - k_param))  (exact)
// e = exp(prod/8) = exp2(prod * log2(e)/8)
__device__ __forceinline__ float score_e(float4 q, float4 k) {
    float c0 = COS2PI(q.x - k.x);
    float c1 = COS2PI(q.y - k.y);
    float c2 = COS2PI(q.z - k.z);
    float c3 = COS2PI(q.w - k.w);
    float prod = (c0 * c1) * (c2 * c3);
    return EXP2F(prod * 0.18033688011112042f); // log2(e)/8
}

// ---------------- Kernel A: angle params ----------------
// One wave per row. Rows [0, B*L*H) -> q rows; [B*L*H, 2*B*L*H) -> k rows.
// Output layout transposed: [B][H][L][P], values tanh(x.W+b)*0.25
__global__ __launch_bounds__(256) void qka_params_kernel(
    const float* __restrict__ Q, const float* __restrict__ K,
    const float* __restrict__ Wq, const float* __restrict__ bq,
    const float* __restrict__ Wk, const float* __restrict__ bk,
    float* __restrict__ qp_ws, float* __restrict__ kp_ws)
{
    const int wid  = (blockIdx.x * blockDim.x + threadIdx.x) >> 6;
    const int lane = threadIdx.x & 63;
    const int NQ = BB * LL * HH;      // 16384
    const bool is_q = (wid < NQ);
    const int r = is_q ? wid : wid - NQ;

    // r = (b*L + l)*H + h
    const int b   = r >> 13;          // / (1024*8)
    const int rem = r & 8191;
    const int l   = rem >> 3;
    const int h   = rem & 7;

    const float* in   = is_q ? Q  : K;
    const float* W    = is_q ? Wq : Wk;
    const float* bias = is_q ? bq : bk;

    float x = in[(size_t)r * DD + lane];
    float4 w = *reinterpret_cast<const float4*>(W + lane * PP); // Wq[d][p], d=lane
    float p0 = x * w.x, p1 = x * w.y, p2 = x * w.z, p3 = x * w.w;
    #pragma unroll
    for (int off = 1; off < 64; off <<= 1) {
        p0 += __shfl_xor(p0, off);
        p1 += __shfl_xor(p1, off);
        p2 += __shfl_xor(p2, off);
        p3 += __shfl_xor(p3, off);
    }
    if (lane < PP) {
        float s = (lane == 0) ? p0 : (lane == 1) ? p1 : (lane == 2) ? p2 : p3;
        float v = 0.25f * tanhf(s + bias[lane]);
        float* outp = is_q ? qp_ws : kp_ws;
        outp[(((size_t)(b * HH + h)) * LL + l) * PP + lane] = v;
    }
}

// ---------------- Kernel B: scores + softmax + attn write + PV ----------------
// grid = B*H*(L/TL) = 512 blocks, 256 threads, 68224 B dynamic LDS (2 blocks/CU)
__global__ __launch_bounds__(256) void qka_attn_kernel(
    const float* __restrict__ V,       // [B,S,H,D]
    const float* __restrict__ qp_ws,   // [B,H,L,P]
    const float* __restrict__ kp_ws,   // [B,H,S,P]
    float* __restrict__ out_ctx,       // [B,L,H,D]
    float* __restrict__ out_attn)      // [B,H,L,S]
{
    extern __shared__ __align__(16) float smem[];
    float* kp   = smem;                 // [S][P]            4096 floats
    float* qp   = kp + SS * PP;         // [TL][P]           128
    float* rcpZ = qp + TL * PP;         // [TL]              32
    float* wbuf = rcpZ + 32;            // [TL][TS]          4096
    float* vbuf = wbuf + TL * TS;       // [TS][68] padded   8704
    // total 17056 floats = 68224 B; ctx-reduce aliases smem (16384 floats)

    const int t   = threadIdx.x;
    const int bid = blockIdx.x;
    const int lt  = bid & 31;
    const int h   = (bid >> 5) & 7;
    const int b   = bid >> 8;

    // ---- stage k-params (full S) and q-params (TL rows) ----
    const float* kp_src = kp_ws + ((size_t)(b * HH + h)) * SS * PP;
    #pragma unroll
    for (int i = 0; i < 4; ++i) {
        int n = i * 256 + t; // float4 index, 1024 total
        *reinterpret_cast<float4*>(kp + n * 4) =
            reinterpret_cast<const float4*>(kp_src)[n];
    }
    const float* qp_src = qp_ws + (((size_t)(b * HH + h)) * LL + lt * TL) * PP;
    if (t < TL * PP) qp[t] = qp_src[t];
    __syncthreads();

    // ---- pass 1: row sums Z (recompute is cheaper than renormalizing 67MB) ----
    {
        const int row = t >> 3;
        const int l8  = t & 7;
        float4 q4 = *reinterpret_cast<const float4*>(qp + row * PP);
        float zsum = 0.f;
        #pragma unroll 8
        for (int i = 0; i < SS / 8; ++i) {
            int s = l8 + i * 8;
            float4 k4 = *reinterpret_cast<const float4*>(kp + s * PP);
            zsum += score_e(q4, k4);
        }
        zsum += __shfl_xor(zsum, 1);
        zsum += __shfl_xor(zsum, 2);
        zsum += __shfl_xor(zsum, 4);
        if (l8 == 0) rcpZ[row] = 1.0f / zsum;
    }

    // ---- pass 2: per s-tile: phase A (w -> LDS + attn store), phase B (PV) ----
    const int rg = t >> 6;          // wave id: rows rg*8 .. rg*8+7
    const int dg = (t >> 3) & 7;    // d block: d = dg*8 .. dg*8+7
    const int sc = t & 7;           // s sub-chunk: s = it*8 + sc

    float acc[8][8];
    #pragma unroll
    for (int i = 0; i < 8; ++i)
        #pragma unroll
        for (int j = 0; j < 8; ++j) acc[i][j] = 0.f;

    for (int tile = 0; tile < NT; ++tile) {
        const int s0 = tile * TS;

        // issue V tile loads early (8 float4 per thread)
        float4 vreg[8];
        #pragma unroll
        for (int i = 0; i < 8; ++i) {
            int n  = i * 256 + t;   // float4 linear idx in tile (2048 total)
            int s  = n >> 4;        // 0..127
            int dq = n & 15;
            vreg[i] = *reinterpret_cast<const float4*>(
                V + (((size_t)(b * SS + s0 + s)) * HH + h) * DD + dq * 4);
        }

        __syncthreads(); // previous phase B finished reading wbuf/vbuf

        // phase A: thread handles s_local = t&127, rows lh*16..lh*16+15
        {
            const int sl = t & 127;
            const int lh = t >> 7;
            float4 k4 = *reinterpret_cast<const float4*>(kp + (s0 + sl) * PP);
            float* attn_base = out_attn +
                (((size_t)(b * HH + h)) * LL + lt * TL + lh * 16) * SS + s0 + sl;
            #pragma unroll
            for (int i = 0; i < 16; ++i) {
                int l = lh * 16 + i;
                float4 q4 = *reinterpret_cast<const float4*>(qp + l * PP);
                float e = score_e(q4, k4);
                float w = e * rcpZ[l];
                wbuf[l * TS + sl] = w;
                attn_base[(size_t)i * SS] = w;
            }
        }

        // commit V tile to LDS (padded stride 68 -> conflict-free b128 reads)
        #pragma unroll
        for (int i = 0; i < 8; ++i) {
            int n  = i * 256 + t;
            int s  = n >> 4;
            int dq = n & 15;
            *reinterpret_cast<float4*>(vbuf + s * 68 + dq * 4) = vreg[i];
        }
        __syncthreads();

        // phase B: register-tiled PV, 64 FMA per 10 LDS reads
        #pragma unroll
        for (int it = 0; it < TS / 8; ++it) {
            int s = it * 8 + sc;
            float w8[8];
            #pragma unroll
            for (int i = 0; i < 8; ++i) w8[i] = wbuf[(rg * 8 + i) * TS + s];
            float4 va = *reinterpret_cast<const float4*>(vbuf + s * 68 + dg * 8);
            float4 vb = *reinterpret_cast<const float4*>(vbuf + s * 68 + dg * 8 + 4);
            #pragma unroll
            for (int i = 0; i < 8; ++i) {
                acc[i][0] += w8[i] * va.x;
                acc[i][1] += w8[i] * va.y;
                acc[i][2] += w8[i] * va.z;
                acc[i][3] += w8[i] * va.w;
                acc[i][4] += w8[i] * vb.x;
                acc[i][5] += w8[i] * vb.y;
                acc[i][6] += w8[i] * vb.z;
                acc[i][7] += w8[i] * vb.w;
            }
        }
    }

    // ---- reduce the 8 s-chunk partial contexts and store ----
    __syncthreads();
    float* ctxbuf = smem; // [8(sc)][TL][DD] = 16384 floats, aliases everything
    #pragma unroll
    for (int i = 0; i < 8; ++i) {
        float* p = ctxbuf + ((sc * TL) + rg * 8 + i) * DD + dg * 8;
        *reinterpret_cast<float4*>(p)     = make_float4(acc[i][0], acc[i][1], acc[i][2], acc[i][3]);
        *reinterpret_cast<float4*>(p + 4) = make_float4(acc[i][4], acc[i][5], acc[i][6], acc[i][7]);
    }
    __syncthreads();
    #pragma unroll
    for (int k = 0; k < 8; ++k) {
        int o = k * 256 + t;  // 0..2047
        int l = o >> 6;
        int d = o & 63;
        float ssum = 0.f;
        #pragma unroll
        for (int scc = 0; scc < 8; ++scc) ssum += ctxbuf[scc * (TL * DD) + o];
        out_ctx[(((size_t)(b * LL + lt * TL + l)) * HH + h) * DD + d] = ssum;
    }
}

extern "C" void kernel_launch(void* const* d_in, const int* in_sizes, int n_in,
                              void* d_out, int out_size, void* d_ws, size_t ws_size,
                              hipStream_t stream) {
    const float* Q  = (const float*)d_in[0];
    const float* K  = (const float*)d_in[1];
    const float* V  = (const float*)d_in[2];
    const float* Wq = (const float*)d_in[3];
    const float* bq = (const float*)d_in[4];
    const float* Wk = (const float*)d_in[5];
    const float* bk = (const float*)d_in[6];

    float* out_ctx  = (float*)d_out;                           // [B,L,H,D]
    float* out_attn = out_ctx + (size_t)BB * LL * HH * DD;     // [B,H,L,S]

    float* qp_ws = (float*)d_ws;                               // 65536 floats
    float* kp_ws = qp_ws + (size_t)BB * HH * LL * PP;          // 65536 floats

    // Kernel A: 32768 rows, one wave each, 4 waves/block
    qka_params_kernel<<<8192, 256, 0, stream>>>(Q, K, Wq, bq, Wk, bk, qp_ws, kp_ws);

    // Kernel B: dynamic LDS 68224 B (>64KB default cap -> raise attribute)
    const int smem_bytes = (SS * PP + TL * PP + 32 + TL * TS + TS * 68) * 4;
    hipFuncSetAttribute((const void*)qka_attn_kernel,
                        hipFuncAttributeMaxDynamicSharedMemorySize, smem_bytes);
    qka_attn_kernel<<<BB * HH * (LL / TL), 256, smem_bytes, stream>>>(
        V, qp_ws, kp_ws, out_ctx, out_attn);
}